// Round 1
// baseline (401.238 us; speedup 1.0000x reference)
//
#include <hip/hip_runtime.h>
#include <stdint.h>

// ScoreMatching: B=2048, D=64, H=512.
// out[b] = 0.5*||s_b||^2 + tr(W4 M3 W3 M2 W2 M1 W1)_b
// Restructured divergence:
//   div_b = sum_{i,d} m2[i] * C[i,d] * G[i,d]
//     C = W2 @ (M1 .* W1)      [512 x 64]  (A = W2,  B^T = m1-masked W1T)
//     G = W3^T @ (M3 .* W4^T)  [512 x 64]  (A = W3T, B^T = m3-masked W4)
// Forward pass in fp32 (precision for the ||s||^2 term); divergence in bf16 MFMA.

#define BATCH 2048
#define DDIM 64
#define HDIM 512

typedef __attribute__((ext_vector_type(8))) short short8;
typedef __attribute__((ext_vector_type(4))) float f32x4;

__device__ __forceinline__ uint16_t f2bf(float f) {
  uint32_t u = __float_as_uint(f);
  uint32_t lsb = (u >> 16) & 1u;
  u += 0x7FFFu + lsb;  // round-to-nearest-even
  return (uint16_t)(u >> 16);
}

// ---------------- convert: fp32 weights -> bf16 (+ transposes) ----------------
// W2bf  [512][512] = W2 row-major
// W3Tbf [512][512] = W3 transposed (W3T[i][j] = W3[j][i])
// W1Tbf [64][512]  = W1 transposed (W1T[d][k] = W1[k][d])
// W4bf  [64][512]  = W4 row-major
__global__ __launch_bounds__(256) void convert_kernel(
    const float* __restrict__ W1, const float* __restrict__ W2,
    const float* __restrict__ W3, const float* __restrict__ W4,
    uint16_t* __restrict__ W2bf, uint16_t* __restrict__ W3Tbf,
    uint16_t* __restrict__ W1Tbf, uint16_t* __restrict__ W4bf) {
  int i = blockIdx.x * 256 + threadIdx.x;
  if (i < 262144) {
    W2bf[i] = f2bf(W2[i]);
  } else if (i < 524288) {
    int j = i - 262144;
    int r = j >> 9, c = j & 511;
    W3Tbf[j] = f2bf(W3[c * 512 + r]);
  } else if (i < 557056) {
    int j = i - 524288;
    int d = j >> 9, k = j & 511;
    W1Tbf[j] = f2bf(W1[k * 64 + d]);
  } else if (i < 589824) {
    int j = i - 557056;
    W4bf[j] = f2bf(W4[j]);
  }
}

// ---------------- forward pass (fp32): masks + 0.5*||s||^2 ----------------
// 4 samples per block of 256 threads; hidden activations staged in LDS.
__device__ __forceinline__ void hidden512(const float* __restrict__ W,
                                          const float* __restrict__ bias,
                                          const float (*__restrict__ hin)[512],
                                          float (*__restrict__ hout)[512],
                                          uint16_t* __restrict__ mu,
                                          int b0, int t) {
#pragma unroll
  for (int jj = 0; jj < 2; ++jj) {
    const int j = t + jj * 256;
    const float4* wr = (const float4*)(W + (size_t)j * 512);
    const float bj = bias[j];
    float c0 = bj, c1 = bj, c2 = bj, c3 = bj;
#pragma unroll 4
    for (int k4 = 0; k4 < 128; ++k4) {
      const float4 w = wr[k4];
      const float4 h0 = *(const float4*)(&hin[0][k4 * 4]);
      const float4 h1 = *(const float4*)(&hin[1][k4 * 4]);
      const float4 h2 = *(const float4*)(&hin[2][k4 * 4]);
      const float4 h3 = *(const float4*)(&hin[3][k4 * 4]);
      c0 = fmaf(w.x, h0.x, c0); c0 = fmaf(w.y, h0.y, c0); c0 = fmaf(w.z, h0.z, c0); c0 = fmaf(w.w, h0.w, c0);
      c1 = fmaf(w.x, h1.x, c1); c1 = fmaf(w.y, h1.y, c1); c1 = fmaf(w.z, h1.z, c1); c1 = fmaf(w.w, h1.w, c1);
      c2 = fmaf(w.x, h2.x, c2); c2 = fmaf(w.y, h2.y, c2); c2 = fmaf(w.z, h2.z, c2); c2 = fmaf(w.w, h2.w, c2);
      c3 = fmaf(w.x, h3.x, c3); c3 = fmaf(w.y, h3.y, c3); c3 = fmaf(w.z, h3.z, c3); c3 = fmaf(w.w, h3.w, c3);
    }
    const float av[4] = {c0, c1, c2, c3};
#pragma unroll
    for (int s = 0; s < 4; ++s) {
      const float a = av[s];
      mu[(size_t)(b0 + s) * 512 + j] = (a > 0.f) ? (uint16_t)0xFFFFu : (uint16_t)0u;
      hout[s][j] = (a > 0.f) ? a : 0.f;
    }
  }
}

__global__ __launch_bounds__(256) void forward_kernel(
    const float* __restrict__ x,
    const float* __restrict__ W1, const float* __restrict__ b1,
    const float* __restrict__ W2, const float* __restrict__ b2,
    const float* __restrict__ W3, const float* __restrict__ b3,
    const float* __restrict__ W4, const float* __restrict__ b4,
    uint16_t* __restrict__ m1u, uint16_t* __restrict__ m2u,
    uint16_t* __restrict__ m3u, float* __restrict__ out) {
  __shared__ float xs[4][64];
  __shared__ float hA[4][512];
  __shared__ float hB[4][512];
  const int t = threadIdx.x;
  const int b0 = blockIdx.x * 4;

  for (int i = t; i < 256; i += 256) xs[i >> 6][i & 63] = x[(size_t)b0 * 64 + i];
  __syncthreads();

  // layer 1: K = 64 (from x)
#pragma unroll
  for (int jj = 0; jj < 2; ++jj) {
    const int j = t + jj * 256;
    const float4* wr = (const float4*)(W1 + (size_t)j * 64);
    const float bj = b1[j];
    float c0 = bj, c1 = bj, c2 = bj, c3 = bj;
#pragma unroll
    for (int k4 = 0; k4 < 16; ++k4) {
      const float4 w = wr[k4];
      const float4 h0 = *(const float4*)(&xs[0][k4 * 4]);
      const float4 h1 = *(const float4*)(&xs[1][k4 * 4]);
      const float4 h2 = *(const float4*)(&xs[2][k4 * 4]);
      const float4 h3 = *(const float4*)(&xs[3][k4 * 4]);
      c0 = fmaf(w.x, h0.x, c0); c0 = fmaf(w.y, h0.y, c0); c0 = fmaf(w.z, h0.z, c0); c0 = fmaf(w.w, h0.w, c0);
      c1 = fmaf(w.x, h1.x, c1); c1 = fmaf(w.y, h1.y, c1); c1 = fmaf(w.z, h1.z, c1); c1 = fmaf(w.w, h1.w, c1);
      c2 = fmaf(w.x, h2.x, c2); c2 = fmaf(w.y, h2.y, c2); c2 = fmaf(w.z, h2.z, c2); c2 = fmaf(w.w, h2.w, c2);
      c3 = fmaf(w.x, h3.x, c3); c3 = fmaf(w.y, h3.y, c3); c3 = fmaf(w.z, h3.z, c3); c3 = fmaf(w.w, h3.w, c3);
    }
    const float av[4] = {c0, c1, c2, c3};
#pragma unroll
    for (int s = 0; s < 4; ++s) {
      const float a = av[s];
      m1u[(size_t)(b0 + s) * 512 + j] = (a > 0.f) ? (uint16_t)0xFFFFu : (uint16_t)0u;
      hA[s][j] = (a > 0.f) ? a : 0.f;
    }
  }
  __syncthreads();
  hidden512(W2, b2, hA, hB, m2u, b0, t);  // layer 2: hA -> hB
  __syncthreads();
  hidden512(W3, b3, hB, hA, m3u, b0, t);  // layer 3: hB -> hA (h3)
  __syncthreads();

  // layer 4: s[d] per thread (wave == sample), then 0.5*||s||^2
  {
    const int s = t >> 6;
    const int d = t & 63;
    const float4* wr = (const float4*)(W4 + (size_t)d * 512);
    float acc = b4[d];
#pragma unroll 4
    for (int k4 = 0; k4 < 128; ++k4) {
      const float4 w = wr[k4];
      const float4 h = *(const float4*)(&hA[s][k4 * 4]);
      acc = fmaf(w.x, h.x, acc); acc = fmaf(w.y, h.y, acc);
      acc = fmaf(w.z, h.z, acc); acc = fmaf(w.w, h.w, acc);
    }
    float sq = acc * acc;
#pragma unroll
    for (int off = 32; off; off >>= 1) sq += __shfl_down(sq, off, 64);
    if (d == 0) out[b0 + s] = 0.5f * sq;
  }
}

// ---------------- divergence: dual bf16 MFMA GEMM + elementwise contraction ----------------
// grid (1024 sample-groups of 2, 4 row-tiles of 128); block 256 = 4 waves.
// wave (sLoc = wv&1, rh = wv>>1): sample g*2+sLoc, rows rowB0 + rh*64 .. +64, cols 0..64.
// Per wave: accC (C GEMM) + accG (G GEMM), 4x4 tiles of 16x16x32 bf16 MFMA.
#define LPAD 48  // LDS row stride in elements (96 B, 16B-aligned, bank-spread)

__global__ __launch_bounds__(256, 2) void div_kernel(
    const uint16_t* __restrict__ W2bf, const uint16_t* __restrict__ W3Tbf,
    const uint16_t* __restrict__ W1Tbf, const uint16_t* __restrict__ W4bf,
    const uint16_t* __restrict__ m1u, const uint16_t* __restrict__ m2u,
    const uint16_t* __restrict__ m3u, float* __restrict__ out) {
  __shared__ uint16_t A2s[128][LPAD];      // W2 tile   [row][k]
  __shared__ uint16_t A3s[128][LPAD];      // W3T tile  [row][k]
  __shared__ uint16_t B1s[2][64][LPAD];    // (m1.*W1T) [sample][d][k]
  __shared__ uint16_t B4s[2][64][LPAD];    // (m3.*W4)  [sample][d][k]

  const int t = threadIdx.x;
  const int lane = t & 63;
  const int wv = t >> 6;
  const int sLoc = wv & 1;
  const int rh = wv >> 1;
  const int l15 = lane & 15;
  const int quad = lane >> 4;
  const int g = blockIdx.x;
  const int rowB0 = blockIdx.y * 128;
  const int b = g * 2 + sLoc;

  f32x4 accC[4][4], accG[4][4];
#pragma unroll
  for (int it = 0; it < 4; ++it)
#pragma unroll
    for (int jt = 0; jt < 4; ++jt) {
      accC[it][jt] = (f32x4){0.f, 0.f, 0.f, 0.f};
      accG[it][jt] = (f32x4){0.f, 0.f, 0.f, 0.f};
    }

  // staging maps: A: 128 rows x 32 k -> thread (row = t>>1, 16 k each)
  const int arow = t >> 1, aseg = t & 1;
  // B: 2 samples x 64 d x 32 k -> thread
  const int sB = t >> 7;
  const int dB = (t & 127) >> 1;
  const int bseg = t & 1;
  const int bS = g * 2 + sB;

  for (int kc = 0; kc < 16; ++kc) {
    const int k0 = kc * 32;
    __syncthreads();
    {
      const uint4* s2 = (const uint4*)(W2bf + (size_t)(rowB0 + arow) * 512 + k0 + aseg * 16);
      const uint4* s3 = (const uint4*)(W3Tbf + (size_t)(rowB0 + arow) * 512 + k0 + aseg * 16);
      uint4* d2 = (uint4*)(&A2s[arow][aseg * 16]);
      uint4* d3 = (uint4*)(&A3s[arow][aseg * 16]);
      d2[0] = s2[0]; d2[1] = s2[1];
      d3[0] = s3[0]; d3[1] = s3[1];
    }
    {
      const uint4* w1p = (const uint4*)(W1Tbf + (size_t)dB * 512 + k0 + bseg * 16);
      const uint4* w4p = (const uint4*)(W4bf + (size_t)dB * 512 + k0 + bseg * 16);
      const uint4* m1p = (const uint4*)(m1u + (size_t)bS * 512 + k0 + bseg * 16);
      const uint4* m3p = (const uint4*)(m3u + (size_t)bS * 512 + k0 + bseg * 16);
      uint4* d1 = (uint4*)(&B1s[sB][dB][bseg * 16]);
      uint4* d4 = (uint4*)(&B4s[sB][dB][bseg * 16]);
#pragma unroll
      for (int i = 0; i < 2; ++i) {
        uint4 w = w1p[i]; uint4 m = m1p[i];
        d1[i] = make_uint4(w.x & m.x, w.y & m.y, w.z & m.z, w.w & m.w);
        w = w4p[i]; m = m3p[i];
        d4[i] = make_uint4(w.x & m.x, w.y & m.y, w.z & m.z, w.w & m.w);
      }
    }
    __syncthreads();

    short8 b1f[4], b4f[4];
#pragma unroll
    for (int jt = 0; jt < 4; ++jt) {
      b1f[jt] = *(const short8*)(&B1s[sLoc][jt * 16 + l15][quad * 8]);
      b4f[jt] = *(const short8*)(&B4s[sLoc][jt * 16 + l15][quad * 8]);
    }
#pragma unroll
    for (int it = 0; it < 4; ++it) {
      const short8 a2 = *(const short8*)(&A2s[rh * 64 + it * 16 + l15][quad * 8]);
      const short8 a3 = *(const short8*)(&A3s[rh * 64 + it * 16 + l15][quad * 8]);
#pragma unroll
      for (int jt = 0; jt < 4; ++jt) {
        accC[it][jt] = __builtin_amdgcn_mfma_f32_16x16x32_bf16(a2, b1f[jt], accC[it][jt], 0, 0, 0);
        accG[it][jt] = __builtin_amdgcn_mfma_f32_16x16x32_bf16(a3, b4f[jt], accG[it][jt], 0, 0, 0);
      }
    }
  }

  // epilogue: dsum = sum m2[row] * C .* G ; C/D layout: row = quad*4+reg, col = l15
  float dsum = 0.f;
#pragma unroll
  for (int it = 0; it < 4; ++it) {
    const int row = rowB0 + rh * 64 + it * 16 + quad * 4;
    const uint2 mm = *(const uint2*)(m2u + (size_t)b * 512 + row);
    const float w0 = (mm.x & 0xFFFFu) ? 1.f : 0.f;
    const float w1 = (mm.x >> 16) ? 1.f : 0.f;
    const float w2 = (mm.y & 0xFFFFu) ? 1.f : 0.f;
    const float w3 = (mm.y >> 16) ? 1.f : 0.f;
#pragma unroll
    for (int jt = 0; jt < 4; ++jt) {
      dsum = fmaf(w0, accC[it][jt][0] * accG[it][jt][0], dsum);
      dsum = fmaf(w1, accC[it][jt][1] * accG[it][jt][1], dsum);
      dsum = fmaf(w2, accC[it][jt][2] * accG[it][jt][2], dsum);
      dsum = fmaf(w3, accC[it][jt][3] * accG[it][jt][3], dsum);
    }
  }
#pragma unroll
  for (int off = 32; off; off >>= 1) dsum += __shfl_down(dsum, off, 64);
  if (lane == 0) atomicAdd(out + b, dsum);
}

extern "C" void kernel_launch(void* const* d_in, const int* in_sizes, int n_in,
                              void* d_out, int out_size, void* d_ws, size_t ws_size,
                              hipStream_t stream) {
  const float* x  = (const float*)d_in[0];
  const float* W1 = (const float*)d_in[1];
  const float* b1 = (const float*)d_in[2];
  const float* W2 = (const float*)d_in[3];
  const float* b2 = (const float*)d_in[4];
  const float* W3 = (const float*)d_in[5];
  const float* b3 = (const float*)d_in[6];
  const float* W4 = (const float*)d_in[7];
  const float* b4 = (const float*)d_in[8];
  float* out = (float*)d_out;

  // workspace layout (uint16 elements): bf16 weights + u16 masks = 7,471,104 B
  uint16_t* ws = (uint16_t*)d_ws;
  uint16_t* W2bf  = ws;                 // 262144
  uint16_t* W3Tbf = ws + 262144;        // 262144
  uint16_t* W1Tbf = ws + 524288;        // 32768
  uint16_t* W4bf  = ws + 557056;        // 32768
  uint16_t* m1u   = ws + 589824;        // 2048*512
  uint16_t* m2u   = m1u + 2048 * 512;
  uint16_t* m3u   = m2u + 2048 * 512;
  if (ws_size < (size_t)(589824 + 3 * 2048 * 512) * 2) return;  // need ~7.2 MB

  convert_kernel<<<2304, 256, 0, stream>>>(W1, W2, W3, W4, W2bf, W3Tbf, W1Tbf, W4bf);
  forward_kernel<<<512, 256, 0, stream>>>(x, W1, b1, W2, b2, W3, b3, W4, b4,
                                          m1u, m2u, m3u, out);
  div_kernel<<<dim3(1024, 4), 256, 0, stream>>>(W2bf, W3Tbf, W1Tbf, W4bf,
                                                m1u, m2u, m3u, out);
}